// Round 5
// baseline (163.115 us; speedup 1.0000x reference)
//
#include <hip/hip_runtime.h>

#define NN 50000
#define NE 800000
#define DD 96
#define HH 32
#define OO 4
#define ELLW 64            // max degree; deg ~ Poisson(16), guarded/clamped
#define NBUCK 196          // 256-node buckets
#define BCAP 8192          // per-bucket edge capacity (mean 4081)

typedef unsigned short ushort_t;
typedef unsigned int uint_t;
typedef __attribute__((ext_vector_type(8))) short short8;
typedef __attribute__((ext_vector_type(4))) float f32x4;

__device__ inline ushort_t f2bf(float f) {
    uint_t b = __float_as_uint(f);
    return (ushort_t)((b + 0x7fffu + ((b >> 16) & 1u)) >> 16);   // RNE
}

__device__ inline void addbf8(float* a, uint4 u) {
    a[0] += __uint_as_float(u.x << 16);
    a[1] += __uint_as_float(u.x & 0xffff0000u);
    a[2] += __uint_as_float(u.y << 16);
    a[3] += __uint_as_float(u.y & 0xffff0000u);
    a[4] += __uint_as_float(u.z << 16);
    a[5] += __uint_as_float(u.z & 0xffff0000u);
    a[6] += __uint_as_float(u.w << 16);
    a[7] += __uint_as_float(u.w & 0xffff0000u);
}

// ====== k1: bucketA | W-frag swizzle | mfma1 (y1 = x@W1a) — all mutually independent ========
// wf layout (shorts): W1b @0 (1152 frags), W2a @9216 (384), W2b @12288 (128), Wh @13312 (64)

#define BA_B   196                           // 4096 edges (1024 quads) per block
#define WF_B   7                             // 1728 frag-threads
#define MT1    (NN / 16)                     // 3125 M tiles
#define MFMA1_B ((MT1 + 3) / 4)              // 782

__global__ void k1(const int* __restrict__ edges, int* __restrict__ bcnt,
                   uint_t* __restrict__ packed,
                   const float* __restrict__ W1b, const float* __restrict__ W2a,
                   const float* __restrict__ W2b, const float* __restrict__ Wh,
                   ushort_t* __restrict__ wf,
                   const float* __restrict__ x, const float* __restrict__ W1a,
                   ushort_t* __restrict__ y1) {
    __shared__ __align__(16) ushort_t lds[1152 * 8];   // 18 KB (mfma1) / hist (bucketA)
    int b = blockIdx.x;
    int thr = threadIdx.x;

    if (b < BA_B) {
        int* hist = (int*)lds;
        int* basesh = hist + NBUCK;
        if (thr < NBUCK) hist[thr] = 0;
        __syncthreads();
#pragma unroll
        for (int k = 0; k < 4; ++k) {
            int t4 = b * 1024 + k * 256 + thr;
            if (t4 < NE / 4) {
                int4 tt = ((const int4*)(edges + NE))[t4];
                atomicAdd(&hist[tt.x >> 8], 1);
                atomicAdd(&hist[tt.y >> 8], 1);
                atomicAdd(&hist[tt.z >> 8], 1);
                atomicAdd(&hist[tt.w >> 8], 1);
            }
        }
        __syncthreads();
        if (thr < NBUCK) {
            int c = hist[thr];
            basesh[thr] = c ? atomicAdd(&bcnt[thr], c) : 0;
        }
        __syncthreads();
        if (thr < NBUCK) hist[thr] = 0;
        __syncthreads();
#pragma unroll
        for (int k = 0; k < 4; ++k) {
            int t4 = b * 1024 + k * 256 + thr;
            if (t4 < NE / 4) {
                int4 ss = ((const int4*)edges)[t4];
                int4 tt = ((const int4*)(edges + NE))[t4];
                int b0 = tt.x >> 8, b1 = tt.y >> 8, b2 = tt.z >> 8, b3 = tt.w >> 8;
                int p0 = basesh[b0] + atomicAdd(&hist[b0], 1);
                int p1 = basesh[b1] + atomicAdd(&hist[b1], 1);
                int p2 = basesh[b2] + atomicAdd(&hist[b2], 1);
                int p3 = basesh[b3] + atomicAdd(&hist[b3], 1);
                if (p0 < BCAP) packed[(size_t)b0 * BCAP + p0] = ((uint_t)ss.x << 8) | (tt.x & 255);
                if (p1 < BCAP) packed[(size_t)b1 * BCAP + p1] = ((uint_t)ss.y << 8) | (tt.y & 255);
                if (p2 < BCAP) packed[(size_t)b2 * BCAP + p2] = ((uint_t)ss.z << 8) | (tt.z & 255);
                if (p3 < BCAP) packed[(size_t)b3 * BCAP + p3] = ((uint_t)ss.w << 8) | (tt.w & 255);
            }
        }
        return;
    }
    b -= BA_B;

    if (b < WF_B) {
        int tw = b * 256 + thr;
        if (tw < 1728) {
            ushort_t v[8];
            ushort_t* dst;
            if (tw < 1152) {                     // W1b: [96][96], KC=3, NT=6
                int fl = tw;
                int lane = fl & 63, fc = fl >> 6;
                int c = fc % 3, nt = fc / 3;
                int kb = c * 32 + (lane >> 4) * 8;
                int col = nt * 16 + (lane & 15);
#pragma unroll
                for (int j = 0; j < 8; ++j) v[j] = f2bf(W1b[(size_t)(kb + j) * DD + col]);
                dst = wf + (size_t)fl * 8;
            } else if (tw < 1536) {              // W2a: [96][32], KC=3, NT=2
                int fl = tw - 1152;
                int lane = fl & 63, fc = fl >> 6;
                int c = fc % 3, nt = fc / 3;
                int kb = c * 32 + (lane >> 4) * 8;
                int col = nt * 16 + (lane & 15);
#pragma unroll
                for (int j = 0; j < 8; ++j) v[j] = f2bf(W2a[(size_t)(kb + j) * HH + col]);
                dst = wf + 9216 + (size_t)fl * 8;
            } else if (tw < 1664) {              // W2b: [32][32], KC=1, NT=2
                int fl = tw - 1536;
                int lane = fl & 63, nt = fl >> 6;
                int kb = (lane >> 4) * 8;
                int col = nt * 16 + (lane & 15);
#pragma unroll
                for (int j = 0; j < 8; ++j) v[j] = f2bf(W2b[(size_t)(kb + j) * HH + col]);
                dst = wf + 12288 + (size_t)fl * 8;
            } else {                             // Wh: [32][4] pad to N=16, KC=1, NT=1
                int fl = tw - 1664;
                int lane = fl;
                int kb = (lane >> 4) * 8;
                int col = lane & 15;
#pragma unroll
                for (int j = 0; j < 8; ++j)
                    v[j] = (col < OO) ? f2bf(Wh[(size_t)(kb + j) * OO + col]) : (ushort_t)0;
                dst = wf + 13312 + (size_t)fl * 8;
            }
            *(uint4*)dst = *(uint4*)v;
        }
        return;
    }
    b -= WF_B;

    // ---- mfma1: cooperative W1a->frag LDS build, then 4 waves x 16-row tiles ----
    constexpr int KC = 3, NT = 6;
    for (int fl = thr; fl < 1152; fl += 256) {
        int lane_f = fl & 63;
        int fc = fl >> 6;                    // nt*3 + c
        int c = fc % 3, nt = fc / 3;
        int kb = c * 32 + (lane_f >> 4) * 8;
        int col = nt * 16 + (lane_f & 15);
        ushort_t v[8];
#pragma unroll
        for (int j = 0; j < 8; ++j)
            v[j] = f2bf(W1a[(size_t)(kb + j) * DD + col]);
        *(uint4*)(lds + (size_t)fl * 8) = *(uint4*)v;
    }
    __syncthreads();

    int lane = thr & 63;
    int widx = thr >> 6;
    int tile = b * 4 + widx;
    if (tile >= MT1) return;
    int row0 = tile * 16;
    int q = lane >> 4;
    int l16 = lane & 15;

    short8 bf[NT][KC];
#pragma unroll
    for (int nt = 0; nt < NT; ++nt)
#pragma unroll
        for (int c = 0; c < KC; ++c)
            bf[nt][c] = *(short8*)(lds + ((size_t)(nt * 3 + c) * 64 + lane) * 8);

    short8 af[KC];
#pragma unroll
    for (int c = 0; c < KC; ++c) {
        const float* ap = x + (size_t)(row0 + l16) * DD + c * 32 + q * 8;
        float4 f0 = *(const float4*)ap;
        float4 f1 = *(const float4*)(ap + 4);
        ushort_t v[8] = {f2bf(f0.x), f2bf(f0.y), f2bf(f0.z), f2bf(f0.w),
                         f2bf(f1.x), f2bf(f1.y), f2bf(f1.z), f2bf(f1.w)};
        af[c] = *(short8*)v;
    }

    f32x4 acc[NT];
#pragma unroll
    for (int nt = 0; nt < NT; ++nt) acc[nt] = (f32x4){0.f, 0.f, 0.f, 0.f};
#pragma unroll
    for (int nt = 0; nt < NT; ++nt)
#pragma unroll
        for (int c = 0; c < KC; ++c)
            acc[nt] = __builtin_amdgcn_mfma_f32_16x16x32_bf16(af[c], bf[nt][c], acc[nt], 0, 0, 0);

    // epilogue: 3 column-slabs [NN][32]
#pragma unroll
    for (int nt = 0; nt < NT; ++nt) {
        int s = nt >> 1;
        int c32 = (nt & 1) * 16 + l16;
#pragma unroll
        for (int r = 0; r < 4; ++r)
            y1[(size_t)s * NN * 32 + (size_t)(row0 + q * 4 + r) * 32 + c32] = f2bf(acc[nt][r]);
    }
}

// ================= k2: bucketB only (ELL fill from packed buckets) ==========================

__global__ void k2(const int* __restrict__ bcnt, const uint_t* __restrict__ packed,
                   ushort_t* __restrict__ ell, int* __restrict__ deg) {
    __shared__ int curL[256];
    int b = blockIdx.x;
    int thr = threadIdx.x;
    int n0 = b * 256;
    curL[thr] = 0;
    __syncthreads();
    int cnt = min(bcnt[b], BCAP);
    const uint_t* pk = packed + (size_t)b * BCAP;
    for (int e = thr; e < cnt; e += 256) {
        uint_t u = pk[e];
        int doff = u & 255;
        int src = u >> 8;
        int p = atomicAdd(&curL[doff], 1);
        if (p < ELLW) ell[(size_t)(n0 + doff) * ELLW + p] = (ushort_t)src;
    }
    __syncthreads();
    if (n0 + thr < NN) deg[n0 + thr] = curL[thr];
}

// ====== k_aggmm: fused agg1 + GEMM2 + GEMM3; 512 thr, 8 thr/node (4 chunks x 2 parts) =======

#define HSTRIDE 104   // 96 + 8 pad shorts

__global__ void k_aggmm(const ushort_t* __restrict__ y1, const int* __restrict__ deg,
                        const ushort_t* __restrict__ ell, const float* __restrict__ eps_p,
                        const float* __restrict__ b1a, const ushort_t* __restrict__ wf,
                        const float* __restrict__ b1b, ushort_t* __restrict__ y2) {
    constexpr int KC = 3, NT1 = 6, NT2 = 2;
    __shared__ __align__(16) ushort_t hT[64 * HSTRIDE];   // 13.3 KB t1 tile (bf16)
    __shared__ __align__(16) ushort_t erL[64 * ELLW];     // 8 KB ELL rows for this block
    __shared__ int degL[64];
    int thr = threadIdx.x;
    int i0 = blockIdx.x * 64;

    // ---- stage ELL + deg once ----
    {
        int r = thr >> 3, c8 = thr & 7;                    // 512 thr = 64 rows x 8 uint4
        int ii = i0 + r;
        uint4 val;
        if (ii < NN) val = ((const uint4*)(ell + (size_t)ii * ELLW))[c8];
        else { val.x = 0; val.y = 0; val.z = 0; val.w = 0; }
        *(uint4*)&erL[r * 64 + c8 * 8] = val;
    }
    if (thr < 64) degL[thr] = (i0 + thr < NN) ? min(deg[i0 + thr], ELLW) : 0;
    __syncthreads();

    int g = thr >> 3;          // node 0..63
    int u = thr & 3;           // 16B chunk within 32-col slab
    int part = (thr >> 2) & 1; // edge partition
    int i = i0 + g;

    if (i < NN) {
        const ushort_t* er = &erL[g * 64];
        int d = degL[g];
        float e = 1.0f + eps_p[0];
        const float4* b4 = (const float4*)b1a;
        ushort_t* dstg = &hT[g * HSTRIDE + u * 8];
#pragma unroll 1
        for (int s = 0; s < 3; ++s) {
            const uint4* ysS = (const uint4*)(y1 + (size_t)s * NN * 32);
            float a0[8] = {0,0,0,0,0,0,0,0}, a1[8] = {0,0,0,0,0,0,0,0};
            float a2[8] = {0,0,0,0,0,0,0,0}, a3[8] = {0,0,0,0,0,0,0,0};
            int p = part;
            for (; p + 6 < d; p += 8) {
                int s0 = er[p], s1 = er[p + 2], s2 = er[p + 4], s3 = er[p + 6];
                uint4 f0 = ysS[(size_t)s0 * 4 + u];
                uint4 f1 = ysS[(size_t)s1 * 4 + u];
                uint4 f2 = ysS[(size_t)s2 * 4 + u];
                uint4 f3 = ysS[(size_t)s3 * 4 + u];
                addbf8(a0, f0); addbf8(a1, f1); addbf8(a2, f2); addbf8(a3, f3);
            }
            for (; p < d; p += 2) addbf8(a0, ysS[(size_t)er[p] * 4 + u]);

            float sm[8];
#pragma unroll
            for (int k = 0; k < 8; ++k) {
                sm[k] = (a0[k] + a1[k]) + (a2[k] + a3[k]);
                sm[k] += __shfl_xor(sm[k], 4);
            }
            if (part == 0) {
                uint4 su = ysS[(size_t)i * 4 + u];
                float s8[8];
                s8[0] = __uint_as_float(su.x << 16); s8[1] = __uint_as_float(su.x & 0xffff0000u);
                s8[2] = __uint_as_float(su.y << 16); s8[3] = __uint_as_float(su.y & 0xffff0000u);
                s8[4] = __uint_as_float(su.z << 16); s8[5] = __uint_as_float(su.z & 0xffff0000u);
                s8[6] = __uint_as_float(su.w << 16); s8[7] = __uint_as_float(su.w & 0xffff0000u);
                float4 bl = b4[s * 8 + u * 2];
                float4 bh2 = b4[s * 8 + u * 2 + 1];
                float bb[8] = {bl.x, bl.y, bl.z, bl.w, bh2.x, bh2.y, bh2.z, bh2.w};
                ushort_t r[8];
#pragma unroll
                for (int k = 0; k < 8; ++k) {
                    float vv = fmaf(e, s8[k], sm[k]) + bb[k];
                    r[k] = f2bf(fmaxf(vv, 0.0f));
                }
                *(uint4*)(dstg + s * 32) = *(uint4*)r;
            }
        }
    }
    __syncthreads();

    // ---- phase 2: GEMM2+3 on the LDS t1 tile (waves 0-3) ----
    int lane = thr & 63;
    int widx = thr >> 6;
    if (widx >= 4) return;
    int tile = blockIdx.x * 4 + widx;
    if (tile >= MT1) return;
    int row0 = tile * 16;
    int q = lane >> 4;
    int l16 = lane & 15;
    const short8* bfp1 = (const short8*)wf;
    const short8* bfp2 = (const short8*)(wf + 9216);

    short8 bf[NT1][KC];
#pragma unroll
    for (int nt = 0; nt < NT1; ++nt)
#pragma unroll
        for (int c = 0; c < KC; ++c)
            bf[nt][c] = bfp1[(nt * KC + c) * 64 + lane];

    short8 af2[KC];
#pragma unroll
    for (int c = 0; c < KC; ++c) {
        uint4 av = *(const uint4*)&hT[(widx * 16 + l16) * HSTRIDE + c * 32 + q * 8];
        af2[c] = *(short8*)&av;
    }

    f32x4 acc[NT1];
#pragma unroll
    for (int nt = 0; nt < NT1; ++nt) acc[nt] = (f32x4){0.f, 0.f, 0.f, 0.f};
#pragma unroll
    for (int nt = 0; nt < NT1; ++nt)
#pragma unroll
        for (int c = 0; c < KC; ++c)
            acc[nt] = __builtin_amdgcn_mfma_f32_16x16x32_bf16(af2[c], bf[nt][c], acc[nt], 0, 0, 0);

    __syncthreads();
#pragma unroll
    for (int nt = 0; nt < NT1; ++nt) {
        int col = nt * 16 + l16;
        float bv = b1b[col];
#pragma unroll
        for (int r = 0; r < 4; ++r)
            hT[(widx * 16 + q * 4 + r) * HSTRIDE + col] = f2bf(fmaxf(acc[nt][r] + bv, 0.0f));
    }
    __syncthreads();

    short8 af3[KC];
#pragma unroll
    for (int c = 0; c < KC; ++c) {
        uint4 av = *(const uint4*)&hT[(widx * 16 + l16) * HSTRIDE + c * 32 + q * 8];
        af3[c] = *(short8*)&av;
    }
    short8 bf2[NT2][KC];
#pragma unroll
    for (int nt = 0; nt < NT2; ++nt)
#pragma unroll
        for (int c = 0; c < KC; ++c)
            bf2[nt][c] = bfp2[(nt * KC + c) * 64 + lane];

    f32x4 acc2[NT2];
#pragma unroll
    for (int nt = 0; nt < NT2; ++nt) acc2[nt] = (f32x4){0.f, 0.f, 0.f, 0.f};
#pragma unroll
    for (int nt = 0; nt < NT2; ++nt)
#pragma unroll
        for (int c = 0; c < KC; ++c)
            acc2[nt] = __builtin_amdgcn_mfma_f32_16x16x32_bf16(af3[c], bf2[nt][c], acc2[nt], 0, 0, 0);

#pragma unroll
    for (int nt = 0; nt < NT2; ++nt) {
        int col = nt * 16 + l16;
#pragma unroll
        for (int r = 0; r < 4; ++r)
            y2[(size_t)(row0 + q * 4 + r) * HH + col] = f2bf(acc2[nt][r]);
    }
}

// ====== k_agg2tail: fused agg2 + MFMA tail; 512 thr, 8 thr/node (4 chunks x 2 parts) ========

#define TS2 40        // 32 + 8 pad shorts

__global__ void k_agg2tail(const ushort_t* __restrict__ y2, const int* __restrict__ deg,
                           const ushort_t* __restrict__ ell, const float* __restrict__ eps_p,
                           const float* __restrict__ b2a, const float* __restrict__ b2b,
                           const float* __restrict__ bhp, const ushort_t* __restrict__ wf,
                           float* __restrict__ out) {
    __shared__ __align__(16) ushort_t erL[64 * ELLW];     // 8 KB
    __shared__ int degL[64];
    __shared__ __align__(16) ushort_t t2T[64 * TS2];      // 5 KB t2 tile (bf16)
    __shared__ __align__(16) ushort_t hB[4][16 * TS2];    // 5 KB h2 bounce
    int thr = threadIdx.x;
    int i0 = blockIdx.x * 64;

    {
        int r = thr >> 3, c8 = thr & 7;
        int ii = i0 + r;
        uint4 val;
        if (ii < NN) val = ((const uint4*)(ell + (size_t)ii * ELLW))[c8];
        else { val.x = 0; val.y = 0; val.z = 0; val.w = 0; }
        *(uint4*)&erL[r * 64 + c8 * 8] = val;
    }
    if (thr < 64) degL[thr] = (i0 + thr < NN) ? min(deg[i0 + thr], ELLW) : 0;
    __syncthreads();

    int g = thr >> 3;
    int u = thr & 3;
    int part = (thr >> 2) & 1;
    int i = i0 + g;

    if (i < NN) {
        const ushort_t* er = &erL[g * 64];
        int d = degL[g];
        const uint4* y4 = (const uint4*)y2;
        float a0[8] = {0,0,0,0,0,0,0,0}, a1[8] = {0,0,0,0,0,0,0,0};
        float a2[8] = {0,0,0,0,0,0,0,0}, a3[8] = {0,0,0,0,0,0,0,0};
        int p = part;
        for (; p + 6 < d; p += 8) {
            int s0 = er[p], s1 = er[p + 2], s2 = er[p + 4], s3 = er[p + 6];
            uint4 f0 = y4[(size_t)s0 * 4 + u];
            uint4 f1 = y4[(size_t)s1 * 4 + u];
            uint4 f2 = y4[(size_t)s2 * 4 + u];
            uint4 f3 = y4[(size_t)s3 * 4 + u];
            addbf8(a0, f0); addbf8(a1, f1); addbf8(a2, f2); addbf8(a3, f3);
        }
        for (; p < d; p += 2) addbf8(a0, y4[(size_t)er[p] * 4 + u]);

        float sm[8];
#pragma unroll
        for (int k = 0; k < 8; ++k) {
            sm[k] = (a0[k] + a1[k]) + (a2[k] + a3[k]);
            sm[k] += __shfl_xor(sm[k], 4);
        }
        if (part == 0) {
            uint4 su = y4[(size_t)i * 4 + u];
            float s8[8];
            s8[0] = __uint_as_float(su.x << 16); s8[1] = __uint_as_float(su.x & 0xffff0000u);
            s8[2] = __uint_as_float(su.y << 16); s8[3] = __uint_as_float(su.y & 0xffff0000u);
            s8[4] = __uint_as_float(su.z << 16); s8[5] = __uint_as_float(su.z & 0xffff0000u);
            s8[6] = __uint_as_float(su.w << 16); s8[7] = __uint_as_float(su.w & 0xffff0000u);
            float4 bl = ((const float4*)b2a)[u * 2];
            float4 bh2 = ((const float4*)b2a)[u * 2 + 1];
            float bb[8] = {bl.x, bl.y, bl.z, bl.w, bh2.x, bh2.y, bh2.z, bh2.w};
            float e = 1.0f + eps_p[0];
            ushort_t r[8];
#pragma unroll
            for (int k = 0; k < 8; ++k) {
                float vv = fmaf(e, s8[k], sm[k]) + bb[k];
                r[k] = f2bf(fmaxf(vv, 0.0f));
            }
            *(uint4*)&t2T[g * TS2 + u * 8] = *(uint4*)r;
        }
    }
    __syncthreads();

    // ---- phase 2: MFMA tail (waves 0-3) ----
    int lane = thr & 63;
    int widx = thr >> 6;
    if (widx >= 4) return;
    int tile = blockIdx.x * 4 + widx;
    if (tile >= MT1) return;
    int row0 = tile * 16;
    int q = lane >> 4;
    int l16 = lane & 15;

    uint4 av = *(const uint4*)&t2T[(widx * 16 + l16) * TS2 + q * 8];
    short8 afA = *(short8*)&av;
    const short8* bfW2b = (const short8*)(wf + 12288);
    const short8* bfWh  = (const short8*)(wf + 13312);

    f32x4 acc2[2];
#pragma unroll
    for (int nt = 0; nt < 2; ++nt) {
        acc2[nt] = (f32x4){0.f, 0.f, 0.f, 0.f};
        acc2[nt] = __builtin_amdgcn_mfma_f32_16x16x32_bf16(afA, bfW2b[nt * 64 + lane],
                                                           acc2[nt], 0, 0, 0);
    }

    // h2 = relu(acc2 + b2b) -> per-wave LDS bounce (intra-wave only)
#pragma unroll
    for (int nt = 0; nt < 2; ++nt) {
        int col = nt * 16 + l16;
        float bv = b2b[col];
#pragma unroll
        for (int r = 0; r < 4; ++r)
            hB[widx][(q * 4 + r) * TS2 + col] = f2bf(fmaxf(acc2[nt][r] + bv, 0.0f));
    }

    uint4 av2 = *(const uint4*)&hB[widx][l16 * TS2 + q * 8];
    short8 afH = *(short8*)&av2;
    f32x4 acch = (f32x4){0.f, 0.f, 0.f, 0.f};
    acch = __builtin_amdgcn_mfma_f32_16x16x32_bf16(afH, bfWh[lane], acch, 0, 0, 0);

    if (l16 < OO) {
        float bv = bhp[l16];
#pragma unroll
        for (int r = 0; r < 4; ++r)
            out[(size_t)(row0 + q * 4 + r) * OO + l16] = acch[r] + bv;
    }
}

// ================= launch =================

extern "C" void kernel_launch(void* const* d_in, const int* in_sizes, int n_in,
                              void* d_out, int out_size, void* d_ws, size_t ws_size,
                              hipStream_t stream) {
    const float* x    = (const float*)d_in[0];
    const int*   edges= (const int*)d_in[1];
    const float* eps1 = (const float*)d_in[2];
    const float* eps2 = (const float*)d_in[3];
    const float* W1a  = (const float*)d_in[4];
    const float* b1a  = (const float*)d_in[5];
    const float* W1b  = (const float*)d_in[6];
    const float* b1b  = (const float*)d_in[7];
    const float* W2a  = (const float*)d_in[8];
    const float* b2a  = (const float*)d_in[9];
    const float* W2b  = (const float*)d_in[10];
    const float* b2b  = (const float*)d_in[11];
    const float* Wh   = (const float*)d_in[12];
    const float* bh   = (const float*)d_in[13];

    auto al = [](size_t n) { return (n + 255) / 256 * 256; };
    char* w = (char*)d_ws;
    int*      bcnt   = (int*)w;      w += al((size_t)NBUCK * 4);
    uint_t*   packed = (uint_t*)w;   w += al((size_t)NBUCK * BCAP * 4);
    int*      deg    = (int*)w;      w += al((size_t)NN * 4);
    ushort_t* ell    = (ushort_t*)w; w += al((size_t)NN * ELLW * 2);
    ushort_t* wf     = (ushort_t*)w; w += al((size_t)13824 * 2);
    ushort_t* y1     = (ushort_t*)w; w += al((size_t)NN * DD * 2);   // 3 slabs of [NN][32]
    ushort_t* y2     = (ushort_t*)w; w += al((size_t)NN * HH * 2);

    hipMemsetAsync(bcnt, 0, (size_t)NBUCK * 4, stream);
    k1<<<BA_B + WF_B + MFMA1_B, 256, 0, stream>>>(edges, bcnt, packed, W1b, W2a, W2b, Wh,
                                                  wf, x, W1a, y1);
    k2<<<NBUCK, 256, 0, stream>>>(bcnt, packed, ell, deg);
    k_aggmm<<<MFMA1_B, 512, 0, stream>>>(y1, deg, ell, eps1, b1a, wf, b1b, y2);
    k_agg2tail<<<MFMA1_B, 512, 0, stream>>>(y2, deg, ell, eps2, b2a, b2b, bh, wf,
                                            (float*)d_out);
}

// Round 6
// 152.994 us; speedup vs baseline: 1.0662x; 1.0662x over previous
//
#include <hip/hip_runtime.h>

#define NN 50000
#define NE 800000
#define DD 96
#define HH 32
#define OO 4
#define ELLW 64            // max degree; deg ~ Poisson(16), guarded/clamped
#define NBUCK 196          // 256-node buckets
#define BCAP 8192          // per-bucket edge capacity (mean 4081)

typedef unsigned short ushort_t;
typedef unsigned int uint_t;
typedef __attribute__((ext_vector_type(8))) short short8;
typedef __attribute__((ext_vector_type(4))) float f32x4;

__device__ inline ushort_t f2bf(float f) {
    uint_t b = __float_as_uint(f);
    return (ushort_t)((b + 0x7fffu + ((b >> 16) & 1u)) >> 16);   // RNE
}

__device__ inline void addbf8(float* a, uint4 u) {
    a[0] += __uint_as_float(u.x << 16);
    a[1] += __uint_as_float(u.x & 0xffff0000u);
    a[2] += __uint_as_float(u.y << 16);
    a[3] += __uint_as_float(u.y & 0xffff0000u);
    a[4] += __uint_as_float(u.z << 16);
    a[5] += __uint_as_float(u.z & 0xffff0000u);
    a[6] += __uint_as_float(u.w << 16);
    a[7] += __uint_as_float(u.w & 0xffff0000u);
}

// ====== k1: bucketA | W-frag swizzle | mfma1 (y1 = x@W1a) — all mutually independent ========
// wf layout (shorts): W1b @0 (1152 frags), W2a @9216 (384), W2b @12288 (128), Wh @13312 (64)

#define BA_B   196                           // 4096 edges (1024 quads) per block
#define WF_B   7                             // 1728 frag-threads
#define MT1    (NN / 16)                     // 3125 M tiles
#define MFMA1_B ((MT1 + 3) / 4)              // 782

__global__ void k1(const int* __restrict__ edges, int* __restrict__ bcnt,
                   uint_t* __restrict__ packed,
                   const float* __restrict__ W1b, const float* __restrict__ W2a,
                   const float* __restrict__ W2b, const float* __restrict__ Wh,
                   ushort_t* __restrict__ wf,
                   const float* __restrict__ x, const float* __restrict__ W1a,
                   ushort_t* __restrict__ y1) {
    __shared__ __align__(16) ushort_t lds[1152 * 8];   // 18 KB (mfma1) / hist (bucketA)
    int b = blockIdx.x;
    int thr = threadIdx.x;

    if (b < BA_B) {
        int* hist = (int*)lds;
        int* basesh = hist + NBUCK;
        if (thr < NBUCK) hist[thr] = 0;
        __syncthreads();
#pragma unroll
        for (int k = 0; k < 4; ++k) {
            int t4 = b * 1024 + k * 256 + thr;
            if (t4 < NE / 4) {
                int4 tt = ((const int4*)(edges + NE))[t4];
                atomicAdd(&hist[tt.x >> 8], 1);
                atomicAdd(&hist[tt.y >> 8], 1);
                atomicAdd(&hist[tt.z >> 8], 1);
                atomicAdd(&hist[tt.w >> 8], 1);
            }
        }
        __syncthreads();
        if (thr < NBUCK) {
            int c = hist[thr];
            basesh[thr] = c ? atomicAdd(&bcnt[thr], c) : 0;
        }
        __syncthreads();
        if (thr < NBUCK) hist[thr] = 0;
        __syncthreads();
#pragma unroll
        for (int k = 0; k < 4; ++k) {
            int t4 = b * 1024 + k * 256 + thr;
            if (t4 < NE / 4) {
                int4 ss = ((const int4*)edges)[t4];
                int4 tt = ((const int4*)(edges + NE))[t4];
                int b0 = tt.x >> 8, b1 = tt.y >> 8, b2 = tt.z >> 8, b3 = tt.w >> 8;
                int p0 = basesh[b0] + atomicAdd(&hist[b0], 1);
                int p1 = basesh[b1] + atomicAdd(&hist[b1], 1);
                int p2 = basesh[b2] + atomicAdd(&hist[b2], 1);
                int p3 = basesh[b3] + atomicAdd(&hist[b3], 1);
                if (p0 < BCAP) packed[(size_t)b0 * BCAP + p0] = ((uint_t)ss.x << 8) | (tt.x & 255);
                if (p1 < BCAP) packed[(size_t)b1 * BCAP + p1] = ((uint_t)ss.y << 8) | (tt.y & 255);
                if (p2 < BCAP) packed[(size_t)b2 * BCAP + p2] = ((uint_t)ss.z << 8) | (tt.z & 255);
                if (p3 < BCAP) packed[(size_t)b3 * BCAP + p3] = ((uint_t)ss.w << 8) | (tt.w & 255);
            }
        }
        return;
    }
    b -= BA_B;

    if (b < WF_B) {
        int tw = b * 256 + thr;
        if (tw < 1728) {
            ushort_t v[8];
            ushort_t* dst;
            if (tw < 1152) {                     // W1b: [96][96], KC=3, NT=6
                int fl = tw;
                int lane = fl & 63, fc = fl >> 6;
                int c = fc % 3, nt = fc / 3;
                int kb = c * 32 + (lane >> 4) * 8;
                int col = nt * 16 + (lane & 15);
#pragma unroll
                for (int j = 0; j < 8; ++j) v[j] = f2bf(W1b[(size_t)(kb + j) * DD + col]);
                dst = wf + (size_t)fl * 8;
            } else if (tw < 1536) {              // W2a: [96][32], KC=3, NT=2
                int fl = tw - 1152;
                int lane = fl & 63, fc = fl >> 6;
                int c = fc % 3, nt = fc / 3;
                int kb = c * 32 + (lane >> 4) * 8;
                int col = nt * 16 + (lane & 15);
#pragma unroll
                for (int j = 0; j < 8; ++j) v[j] = f2bf(W2a[(size_t)(kb + j) * HH + col]);
                dst = wf + 9216 + (size_t)fl * 8;
            } else if (tw < 1664) {              // W2b: [32][32], KC=1, NT=2
                int fl = tw - 1536;
                int lane = fl & 63, nt = fl >> 6;
                int kb = (lane >> 4) * 8;
                int col = nt * 16 + (lane & 15);
#pragma unroll
                for (int j = 0; j < 8; ++j) v[j] = f2bf(W2b[(size_t)(kb + j) * HH + col]);
                dst = wf + 12288 + (size_t)fl * 8;
            } else {                             // Wh: [32][4] pad to N=16, KC=1, NT=1
                int fl = tw - 1664;
                int lane = fl;
                int kb = (lane >> 4) * 8;
                int col = lane & 15;
#pragma unroll
                for (int j = 0; j < 8; ++j)
                    v[j] = (col < OO) ? f2bf(Wh[(size_t)(kb + j) * OO + col]) : (ushort_t)0;
                dst = wf + 13312 + (size_t)fl * 8;
            }
            *(uint4*)dst = *(uint4*)v;
        }
        return;
    }
    b -= WF_B;

    // ---- mfma1: cooperative W1a->frag LDS build, then 4 waves x 16-row tiles ----
    constexpr int KC = 3, NT = 6;
    for (int fl = thr; fl < 1152; fl += 256) {
        int lane_f = fl & 63;
        int fc = fl >> 6;                    // nt*3 + c
        int c = fc % 3, nt = fc / 3;
        int kb = c * 32 + (lane_f >> 4) * 8;
        int col = nt * 16 + (lane_f & 15);
        ushort_t v[8];
#pragma unroll
        for (int j = 0; j < 8; ++j)
            v[j] = f2bf(W1a[(size_t)(kb + j) * DD + col]);
        *(uint4*)(lds + (size_t)fl * 8) = *(uint4*)v;
    }
    __syncthreads();

    int lane = thr & 63;
    int widx = thr >> 6;
    int tile = b * 4 + widx;
    if (tile >= MT1) return;
    int row0 = tile * 16;
    int q = lane >> 4;
    int l16 = lane & 15;

    short8 bf[NT][KC];
#pragma unroll
    for (int nt = 0; nt < NT; ++nt)
#pragma unroll
        for (int c = 0; c < KC; ++c)
            bf[nt][c] = *(short8*)(lds + ((size_t)(nt * 3 + c) * 64 + lane) * 8);

    short8 af[KC];
#pragma unroll
    for (int c = 0; c < KC; ++c) {
        const float* ap = x + (size_t)(row0 + l16) * DD + c * 32 + q * 8;
        float4 f0 = *(const float4*)ap;
        float4 f1 = *(const float4*)(ap + 4);
        ushort_t v[8] = {f2bf(f0.x), f2bf(f0.y), f2bf(f0.z), f2bf(f0.w),
                         f2bf(f1.x), f2bf(f1.y), f2bf(f1.z), f2bf(f1.w)};
        af[c] = *(short8*)v;
    }

    f32x4 acc[NT];
#pragma unroll
    for (int nt = 0; nt < NT; ++nt) acc[nt] = (f32x4){0.f, 0.f, 0.f, 0.f};
#pragma unroll
    for (int nt = 0; nt < NT; ++nt)
#pragma unroll
        for (int c = 0; c < KC; ++c)
            acc[nt] = __builtin_amdgcn_mfma_f32_16x16x32_bf16(af[c], bf[nt][c], acc[nt], 0, 0, 0);

    // epilogue: 3 column-slabs [NN][32]
#pragma unroll
    for (int nt = 0; nt < NT; ++nt) {
        int s = nt >> 1;
        int c32 = (nt & 1) * 16 + l16;
#pragma unroll
        for (int r = 0; r < 4; ++r)
            y1[(size_t)s * NN * 32 + (size_t)(row0 + q * 4 + r) * 32 + c32] = f2bf(acc[nt][r]);
    }
}

// ================= k2: bucketB only (ELL fill from packed buckets) ==========================

__global__ void k2(const int* __restrict__ bcnt, const uint_t* __restrict__ packed,
                   ushort_t* __restrict__ ell, int* __restrict__ deg) {
    __shared__ int curL[256];
    int b = blockIdx.x;
    int thr = threadIdx.x;
    int n0 = b * 256;
    curL[thr] = 0;
    __syncthreads();
    int cnt = min(bcnt[b], BCAP);
    const uint_t* pk = packed + (size_t)b * BCAP;
    for (int e = thr; e < cnt; e += 256) {
        uint_t u = pk[e];
        int doff = u & 255;
        int src = u >> 8;
        int p = atomicAdd(&curL[doff], 1);
        if (p < ELLW) ell[(size_t)(n0 + doff) * ELLW + p] = (ushort_t)src;
    }
    __syncthreads();
    if (n0 + thr < NN) deg[n0 + thr] = curL[thr];
}

// ====== k_aggmm: fused agg1 + GEMM2 + GEMM3, slab-phased gather, ELL staged in LDS ==========
// (round-4 proven version: 256 thr, 4 thr/node)

#define HSTRIDE 104   // 96 + 8 pad shorts

__global__ void k_aggmm(const ushort_t* __restrict__ y1, const int* __restrict__ deg,
                        const ushort_t* __restrict__ ell, const float* __restrict__ eps_p,
                        const float* __restrict__ b1a, const ushort_t* __restrict__ wf,
                        const float* __restrict__ b1b, ushort_t* __restrict__ y2) {
    constexpr int KC = 3, NT1 = 6, NT2 = 2;
    __shared__ __align__(16) ushort_t hT[64 * HSTRIDE];   // 13.3 KB t1 tile (bf16)
    __shared__ __align__(16) ushort_t erL[64 * ELLW];     // 8 KB ELL rows for this block
    __shared__ int degL[64];
    int thr = threadIdx.x;
    int i0 = blockIdx.x * 64;

    // ---- stage ELL + deg once (read from global exactly once per block) ----
    for (int t = thr; t < 64 * 8; t += 256) {              // 64 rows x 8 uint4 (128B/row)
        int r = t >> 3, c8 = t & 7;
        int ii = i0 + r;
        uint4 val;
        if (ii < NN) val = ((const uint4*)(ell + (size_t)ii * ELLW))[c8];
        else { val.x = 0; val.y = 0; val.z = 0; val.w = 0; }
        *(uint4*)&erL[r * 64 + c8 * 8] = val;
    }
    if (thr < 64) degL[thr] = (i0 + thr < NN) ? min(deg[i0 + thr], ELLW) : 0;
    __syncthreads();

    int g = thr >> 2;          // node 0..63 within block
    int u = thr & 3;           // 16B chunk within each 32-col slab
    int i = i0 + g;

    if (i < NN) {
        const ushort_t* er = &erL[g * 64];
        int d = degL[g];
        float e = 1.0f + eps_p[0];
        const float4* b4 = (const float4*)b1a;
        ushort_t* dstg = &hT[g * HSTRIDE + u * 8];
#pragma unroll 1
        for (int s = 0; s < 3; ++s) {
            const uint4* ysS = (const uint4*)(y1 + (size_t)s * NN * 32);
            float a0[8] = {0,0,0,0,0,0,0,0}, a1[8] = {0,0,0,0,0,0,0,0};
            float a2[8] = {0,0,0,0,0,0,0,0}, a3[8] = {0,0,0,0,0,0,0,0};
            int p = 0;
            for (; p + 3 < d; p += 4) {
                int s0 = er[p], s1 = er[p + 1], s2 = er[p + 2], s3 = er[p + 3];
                uint4 f0 = ysS[(size_t)s0 * 4 + u];
                uint4 f1 = ysS[(size_t)s1 * 4 + u];
                uint4 f2 = ysS[(size_t)s2 * 4 + u];
                uint4 f3 = ysS[(size_t)s3 * 4 + u];
                addbf8(a0, f0); addbf8(a1, f1); addbf8(a2, f2); addbf8(a3, f3);
            }
            for (; p < d; ++p) addbf8(a0, ysS[(size_t)er[p] * 4 + u]);

            uint4 su = ysS[(size_t)i * 4 + u];
            float s8[8];
            s8[0] = __uint_as_float(su.x << 16); s8[1] = __uint_as_float(su.x & 0xffff0000u);
            s8[2] = __uint_as_float(su.y << 16); s8[3] = __uint_as_float(su.y & 0xffff0000u);
            s8[4] = __uint_as_float(su.z << 16); s8[5] = __uint_as_float(su.z & 0xffff0000u);
            s8[6] = __uint_as_float(su.w << 16); s8[7] = __uint_as_float(su.w & 0xffff0000u);
            float4 bl = b4[s * 8 + u * 2];
            float4 bh2 = b4[s * 8 + u * 2 + 1];
            float bb[8] = {bl.x, bl.y, bl.z, bl.w, bh2.x, bh2.y, bh2.z, bh2.w};
            ushort_t r[8];
#pragma unroll
            for (int k = 0; k < 8; ++k) {
                float vv = fmaf(e, s8[k], (a0[k] + a1[k]) + (a2[k] + a3[k])) + bb[k];
                r[k] = f2bf(fmaxf(vv, 0.0f));
            }
            *(uint4*)(dstg + s * 32) = *(uint4*)r;
        }
    }
    __syncthreads();

    // ---- phase 2: GEMM2+3 on the LDS t1 tile ----
    int lane = thr & 63;
    int widx = thr >> 6;
    int tile = blockIdx.x * 4 + widx;
    if (tile >= MT1) return;
    int row0 = tile * 16;
    int q = lane >> 4;
    int l16 = lane & 15;
    const short8* bfp1 = (const short8*)wf;
    const short8* bfp2 = (const short8*)(wf + 9216);

    short8 bf[NT1][KC];
#pragma unroll
    for (int nt = 0; nt < NT1; ++nt)
#pragma unroll
        for (int c = 0; c < KC; ++c)
            bf[nt][c] = bfp1[(nt * KC + c) * 64 + lane];

    short8 af2[KC];
#pragma unroll
    for (int c = 0; c < KC; ++c) {
        uint4 av = *(const uint4*)&hT[(widx * 16 + l16) * HSTRIDE + c * 32 + q * 8];
        af2[c] = *(short8*)&av;
    }

    f32x4 acc[NT1];
#pragma unroll
    for (int nt = 0; nt < NT1; ++nt) acc[nt] = (f32x4){0.f, 0.f, 0.f, 0.f};
#pragma unroll
    for (int nt = 0; nt < NT1; ++nt)
#pragma unroll
        for (int c = 0; c < KC; ++c)
            acc[nt] = __builtin_amdgcn_mfma_f32_16x16x32_bf16(af2[c], bf[nt][c], acc[nt], 0, 0, 0);

    __syncthreads();
#pragma unroll
    for (int nt = 0; nt < NT1; ++nt) {
        int col = nt * 16 + l16;
        float bv = b1b[col];
#pragma unroll
        for (int r = 0; r < 4; ++r)
            hT[(widx * 16 + q * 4 + r) * HSTRIDE + col] = f2bf(fmaxf(acc[nt][r] + bv, 0.0f));
    }
    __syncthreads();

    short8 af3[KC];
#pragma unroll
    for (int c = 0; c < KC; ++c) {
        uint4 av = *(const uint4*)&hT[(widx * 16 + l16) * HSTRIDE + c * 32 + q * 8];
        af3[c] = *(short8*)&av;
    }
    short8 bf2[NT2][KC];
#pragma unroll
    for (int nt = 0; nt < NT2; ++nt)
#pragma unroll
        for (int c = 0; c < KC; ++c)
            bf2[nt][c] = bfp2[(nt * KC + c) * 64 + lane];

    f32x4 acc2[NT2];
#pragma unroll
    for (int nt = 0; nt < NT2; ++nt) acc2[nt] = (f32x4){0.f, 0.f, 0.f, 0.f};
#pragma unroll
    for (int nt = 0; nt < NT2; ++nt)
#pragma unroll
        for (int c = 0; c < KC; ++c)
            acc2[nt] = __builtin_amdgcn_mfma_f32_16x16x32_bf16(af3[c], bf2[nt][c], acc2[nt], 0, 0, 0);

#pragma unroll
    for (int nt = 0; nt < NT2; ++nt) {
        int col = nt * 16 + l16;
#pragma unroll
        for (int r = 0; r < 4; ++r)
            y2[(size_t)(row0 + q * 4 + r) * HH + col] = f2bf(acc2[nt][r]);
    }
}

// ====== k_agg2tail: fused agg2 + MFMA tail (round-4 proven version: 256 thr, 4 thr/node) ====

#define TS2 40        // 32 + 8 pad shorts

__global__ void k_agg2tail(const ushort_t* __restrict__ y2, const int* __restrict__ deg,
                           const ushort_t* __restrict__ ell, const float* __restrict__ eps_p,
                           const float* __restrict__ b2a, const float* __restrict__ b2b,
                           const float* __restrict__ bhp, const ushort_t* __restrict__ wf,
                           float* __restrict__ out) {
    __shared__ __align__(16) ushort_t erL[64 * ELLW];     // 8 KB
    __shared__ int degL[64];
    __shared__ __align__(16) ushort_t t2T[64 * TS2];      // 5 KB t2 tile (bf16)
    __shared__ __align__(16) ushort_t hB[4][16 * TS2];    // 5 KB h2 bounce
    int thr = threadIdx.x;
    int i0 = blockIdx.x * 64;

    for (int t = thr; t < 64 * 8; t += 256) {
        int r = t >> 3, c8 = t & 7;
        int ii = i0 + r;
        uint4 val;
        if (ii < NN) val = ((const uint4*)(ell + (size_t)ii * ELLW))[c8];
        else { val.x = 0; val.y = 0; val.z = 0; val.w = 0; }
        *(uint4*)&erL[r * 64 + c8 * 8] = val;
    }
    if (thr < 64) degL[thr] = (i0 + thr < NN) ? min(deg[i0 + thr], ELLW) : 0;
    __syncthreads();

    int g = thr >> 2;
    int u = thr & 3;
    int i = i0 + g;

    if (i < NN) {
        const ushort_t* er = &erL[g * 64];
        int d = degL[g];
        const uint4* y4 = (const uint4*)y2;
        float a0[8] = {0,0,0,0,0,0,0,0}, a1[8] = {0,0,0,0,0,0,0,0};
        float a2[8] = {0,0,0,0,0,0,0,0}, a3[8] = {0,0,0,0,0,0,0,0};
        int p = 0;
        for (; p + 3 < d; p += 4) {
            int s0 = er[p], s1 = er[p + 1], s2 = er[p + 2], s3 = er[p + 3];
            uint4 f0 = y4[(size_t)s0 * 4 + u];
            uint4 f1 = y4[(size_t)s1 * 4 + u];
            uint4 f2 = y4[(size_t)s2 * 4 + u];
            uint4 f3 = y4[(size_t)s3 * 4 + u];
            addbf8(a0, f0); addbf8(a1, f1); addbf8(a2, f2); addbf8(a3, f3);
        }
        for (; p < d; ++p) addbf8(a0, y4[(size_t)er[p] * 4 + u]);

        uint4 su = y4[(size_t)i * 4 + u];
        float s8[8];
        s8[0] = __uint_as_float(su.x << 16); s8[1] = __uint_as_float(su.x & 0xffff0000u);
        s8[2] = __uint_as_float(su.y << 16); s8[3] = __uint_as_float(su.y & 0xffff0000u);
        s8[4] = __uint_as_float(su.z << 16); s8[5] = __uint_as_float(su.z & 0xffff0000u);
        s8[6] = __uint_as_float(su.w << 16); s8[7] = __uint_as_float(su.w & 0xffff0000u);
        float4 bl = ((const float4*)b2a)[u * 2];
        float4 bh2 = ((const float4*)b2a)[u * 2 + 1];
        float bb[8] = {bl.x, bl.y, bl.z, bl.w, bh2.x, bh2.y, bh2.z, bh2.w};
        float e = 1.0f + eps_p[0];
        ushort_t r[8];
#pragma unroll
        for (int k = 0; k < 8; ++k) {
            float vv = fmaf(e, s8[k], (a0[k] + a1[k]) + (a2[k] + a3[k])) + bb[k];
            r[k] = f2bf(fmaxf(vv, 0.0f));
        }
        *(uint4*)&t2T[g * TS2 + u * 8] = *(uint4*)r;
    }
    __syncthreads();

    // ---- phase 2: MFMA tail ----
    int lane = thr & 63;
    int widx = thr >> 6;
    int tile = blockIdx.x * 4 + widx;
    if (tile >= MT1) return;
    int row0 = tile * 16;
    int q = lane >> 4;
    int l16 = lane & 15;

    uint4 av = *(const uint4*)&t2T[(widx * 16 + l16) * TS2 + q * 8];
    short8 afA = *(short8*)&av;
    const short8* bfW2b = (const short8*)(wf + 12288);
    const short8* bfWh  = (const short8*)(wf + 13312);

    f32x4 acc2[2];
#pragma unroll
    for (int nt = 0; nt < 2; ++nt) {
        acc2[nt] = (f32x4){0.f, 0.f, 0.f, 0.f};
        acc2[nt] = __builtin_amdgcn_mfma_f32_16x16x32_bf16(afA, bfW2b[nt * 64 + lane],
                                                           acc2[nt], 0, 0, 0);
    }

    // h2 = relu(acc2 + b2b) -> per-wave LDS bounce (intra-wave only; no barrier needed)
#pragma unroll
    for (int nt = 0; nt < 2; ++nt) {
        int col = nt * 16 + l16;
        float bv = b2b[col];
#pragma unroll
        for (int r = 0; r < 4; ++r)
            hB[widx][(q * 4 + r) * TS2 + col] = f2bf(fmaxf(acc2[nt][r] + bv, 0.0f));
    }

    uint4 av2 = *(const uint4*)&hB[widx][l16 * TS2 + q * 8];
    short8 afH = *(short8*)&av2;
    f32x4 acch = (f32x4){0.f, 0.f, 0.f, 0.f};
    acch = __builtin_amdgcn_mfma_f32_16x16x32_bf16(afH, bfWh[lane], acch, 0, 0, 0);

    if (l16 < OO) {
        float bv = bhp[l16];
#pragma unroll
        for (int r = 0; r < 4; ++r)
            out[(size_t)(row0 + q * 4 + r) * OO + l16] = acch[r] + bv;
    }
}

// ================= launch =================

extern "C" void kernel_launch(void* const* d_in, const int* in_sizes, int n_in,
                              void* d_out, int out_size, void* d_ws, size_t ws_size,
                              hipStream_t stream) {
    const float* x    = (const float*)d_in[0];
    const int*   edges= (const int*)d_in[1];
    const float* eps1 = (const float*)d_in[2];
    const float* eps2 = (const float*)d_in[3];
    const float* W1a  = (const float*)d_in[4];
    const float* b1a  = (const float*)d_in[5];
    const float* W1b  = (const float*)d_in[6];
    const float* b1b  = (const float*)d_in[7];
    const float* W2a  = (const float*)d_in[8];
    const float* b2a  = (const float*)d_in[9];
    const float* W2b  = (const float*)d_in[10];
    const float* b2b  = (const float*)d_in[11];
    const float* Wh   = (const float*)d_in[12];
    const float* bh   = (const float*)d_in[13];

    auto al = [](size_t n) { return (n + 255) / 256 * 256; };
    char* w = (char*)d_ws;
    int*      bcnt   = (int*)w;      w += al((size_t)NBUCK * 4);
    uint_t*   packed = (uint_t*)w;   w += al((size_t)NBUCK * BCAP * 4);
    int*      deg    = (int*)w;      w += al((size_t)NN * 4);
    ushort_t* ell    = (ushort_t*)w; w += al((size_t)NN * ELLW * 2);
    ushort_t* wf     = (ushort_t*)w; w += al((size_t)13824 * 2);
    ushort_t* y1     = (ushort_t*)w; w += al((size_t)NN * DD * 2);   // 3 slabs of [NN][32]
    ushort_t* y2     = (ushort_t*)w; w += al((size_t)NN * HH * 2);

    hipMemsetAsync(bcnt, 0, (size_t)NBUCK * 4, stream);
    k1<<<BA_B + WF_B + MFMA1_B, 256, 0, stream>>>(edges, bcnt, packed, W1b, W2a, W2b, Wh,
                                                  wf, x, W1a, y1);
    k2<<<NBUCK, 256, 0, stream>>>(bcnt, packed, ell, deg);
    k_aggmm<<<MFMA1_B, 256, 0, stream>>>(y1, deg, ell, eps1, b1a, wf, b1b, y2);
    k_agg2tail<<<(NN + 63) / 64, 256, 0, stream>>>(y2, deg, ell, eps2, b2a, b2b, bh, wf,
                                                   (float*)d_out);
}

// Round 9
// 151.158 us; speedup vs baseline: 1.0791x; 1.0121x over previous
//
#include <hip/hip_runtime.h>

#define NN 50000
#define NE 800000
#define DD 96
#define HH 32
#define OO 4
#define ELLW 64            // max degree; deg ~ Poisson(16), guarded/clamped
#define NBUCK 196          // 256-node buckets
#define BCAP 8192          // per-bucket edge capacity (mean 4081)

typedef unsigned short ushort_t;
typedef unsigned int uint_t;
typedef __attribute__((ext_vector_type(8))) short short8;
typedef __attribute__((ext_vector_type(4))) float f32x4;

__device__ inline ushort_t f2bf(float f) {
    uint_t b = __float_as_uint(f);
    return (ushort_t)((b + 0x7fffu + ((b >> 16) & 1u)) >> 16);   // RNE
}

__device__ inline void addbf8(float* a, uint4 u) {
    a[0] += __uint_as_float(u.x << 16);
    a[1] += __uint_as_float(u.x & 0xffff0000u);
    a[2] += __uint_as_float(u.y << 16);
    a[3] += __uint_as_float(u.y & 0xffff0000u);
    a[4] += __uint_as_float(u.z << 16);
    a[5] += __uint_as_float(u.z & 0xffff0000u);
    a[6] += __uint_as_float(u.w << 16);
    a[7] += __uint_as_float(u.w & 0xffff0000u);
}

// per-block ELL build straight from the bucket's packed list (no global ELL table).
// block covers nodes [i0, i0+64) ⊂ bucket i0>>8; filter window w0 = i0 & 255.
__device__ inline void build_ell_lds(const int* __restrict__ bcnt,
                                     const uint_t* __restrict__ packed,
                                     int i0, int thr,
                                     ushort_t* erL, int* cntL) {
    if (thr < 64) cntL[thr] = 0;
    __syncthreads();
    int bk = i0 >> 8;
    int w0 = i0 & 255;
    int cnt = min(bcnt[bk], BCAP);
    const uint_t* pk = packed + (size_t)bk * BCAP;
    for (int e = thr; e < cnt; e += 256) {
        uint_t u = pk[e];
        int doff = (int)(u & 255u) - w0;
        if ((unsigned)doff < 64u) {
            int p = atomicAdd(&cntL[doff], 1);
            if (p < ELLW) erL[doff * 64 + p] = (ushort_t)(u >> 8);
        }
    }
    __syncthreads();
}

// ====== k1: bucketA | W-frag swizzle | mfma1 (y1 = x@W1a) — all mutually independent ========
// wf layout (shorts): W1b @0 (1152 frags), W2a @9216 (384), W2b @12288 (128), Wh @13312 (64)

#define BA_B   196                           // 4096 edges (1024 quads) per block
#define WF_B   7                             // 1728 frag-threads
#define MT1    (NN / 16)                     // 3125 M tiles
#define MFMA1_B ((MT1 + 3) / 4)              // 782

__global__ void k1(const int* __restrict__ edges, int* __restrict__ bcnt,
                   uint_t* __restrict__ packed,
                   const float* __restrict__ W1b, const float* __restrict__ W2a,
                   const float* __restrict__ W2b, const float* __restrict__ Wh,
                   ushort_t* __restrict__ wf,
                   const float* __restrict__ x, const float* __restrict__ W1a,
                   ushort_t* __restrict__ y1) {
    __shared__ __align__(16) ushort_t lds[1152 * 8];   // 18 KB (mfma1) / hist (bucketA)
    int b = blockIdx.x;
    int thr = threadIdx.x;

    if (b < BA_B) {
        int* hist = (int*)lds;
        int* basesh = hist + NBUCK;
        if (thr < NBUCK) hist[thr] = 0;
        __syncthreads();
#pragma unroll
        for (int k = 0; k < 4; ++k) {
            int t4 = b * 1024 + k * 256 + thr;
            if (t4 < NE / 4) {
                int4 tt = ((const int4*)(edges + NE))[t4];
                atomicAdd(&hist[tt.x >> 8], 1);
                atomicAdd(&hist[tt.y >> 8], 1);
                atomicAdd(&hist[tt.z >> 8], 1);
                atomicAdd(&hist[tt.w >> 8], 1);
            }
        }
        __syncthreads();
        if (thr < NBUCK) {
            int c = hist[thr];
            basesh[thr] = c ? atomicAdd(&bcnt[thr], c) : 0;
        }
        __syncthreads();
        if (thr < NBUCK) hist[thr] = 0;
        __syncthreads();
#pragma unroll
        for (int k = 0; k < 4; ++k) {
            int t4 = b * 1024 + k * 256 + thr;
            if (t4 < NE / 4) {
                int4 ss = ((const int4*)edges)[t4];
                int4 tt = ((const int4*)(edges + NE))[t4];
                int b0 = tt.x >> 8, b1 = tt.y >> 8, b2 = tt.z >> 8, b3 = tt.w >> 8;
                int p0 = basesh[b0] + atomicAdd(&hist[b0], 1);
                int p1 = basesh[b1] + atomicAdd(&hist[b1], 1);
                int p2 = basesh[b2] + atomicAdd(&hist[b2], 1);
                int p3 = basesh[b3] + atomicAdd(&hist[b3], 1);
                if (p0 < BCAP) packed[(size_t)b0 * BCAP + p0] = ((uint_t)ss.x << 8) | (tt.x & 255);
                if (p1 < BCAP) packed[(size_t)b1 * BCAP + p1] = ((uint_t)ss.y << 8) | (tt.y & 255);
                if (p2 < BCAP) packed[(size_t)b2 * BCAP + p2] = ((uint_t)ss.z << 8) | (tt.z & 255);
                if (p3 < BCAP) packed[(size_t)b3 * BCAP + p3] = ((uint_t)ss.w << 8) | (tt.w & 255);
            }
        }
        return;
    }
    b -= BA_B;

    if (b < WF_B) {
        int tw = b * 256 + thr;
        if (tw < 1728) {
            ushort_t v[8];
            ushort_t* dst;
            if (tw < 1152) {                     // W1b: [96][96], KC=3, NT=6
                int fl = tw;
                int lane = fl & 63, fc = fl >> 6;
                int c = fc % 3, nt = fc / 3;
                int kb = c * 32 + (lane >> 4) * 8;
                int col = nt * 16 + (lane & 15);
#pragma unroll
                for (int j = 0; j < 8; ++j) v[j] = f2bf(W1b[(size_t)(kb + j) * DD + col]);
                dst = wf + (size_t)fl * 8;
            } else if (tw < 1536) {              // W2a: [96][32], KC=3, NT=2
                int fl = tw - 1152;
                int lane = fl & 63, fc = fl >> 6;
                int c = fc % 3, nt = fc / 3;
                int kb = c * 32 + (lane >> 4) * 8;
                int col = nt * 16 + (lane & 15);
#pragma unroll
                for (int j = 0; j < 8; ++j) v[j] = f2bf(W2a[(size_t)(kb + j) * HH + col]);
                dst = wf + 9216 + (size_t)fl * 8;
            } else if (tw < 1664) {              // W2b: [32][32], KC=1, NT=2
                int fl = tw - 1536;
                int lane = fl & 63, nt = fl >> 6;
                int kb = (lane >> 4) * 8;
                int col = nt * 16 + (lane & 15);
#pragma unroll
                for (int j = 0; j < 8; ++j) v[j] = f2bf(W2b[(size_t)(kb + j) * HH + col]);
                dst = wf + 12288 + (size_t)fl * 8;
            } else {                             // Wh: [32][4] pad to N=16, KC=1, NT=1
                int fl = tw - 1664;
                int lane = fl;
                int kb = (lane >> 4) * 8;
                int col = lane & 15;
#pragma unroll
                for (int j = 0; j < 8; ++j)
                    v[j] = (col < OO) ? f2bf(Wh[(size_t)(kb + j) * OO + col]) : (ushort_t)0;
                dst = wf + 13312 + (size_t)fl * 8;
            }
            *(uint4*)dst = *(uint4*)v;
        }
        return;
    }
    b -= WF_B;

    // ---- mfma1: cooperative W1a->frag LDS build, then 4 waves x 16-row tiles ----
    constexpr int KC = 3, NT = 6;
    for (int fl = thr; fl < 1152; fl += 256) {
        int lane_f = fl & 63;
        int fc = fl >> 6;                    // nt*3 + c
        int c = fc % 3, nt = fc / 3;
        int kb = c * 32 + (lane_f >> 4) * 8;
        int col = nt * 16 + (lane_f & 15);
        ushort_t v[8];
#pragma unroll
        for (int j = 0; j < 8; ++j)
            v[j] = f2bf(W1a[(size_t)(kb + j) * DD + col]);
        *(uint4*)(lds + (size_t)fl * 8) = *(uint4*)v;
    }
    __syncthreads();

    int lane = thr & 63;
    int widx = thr >> 6;
    int tile = b * 4 + widx;
    if (tile >= MT1) return;
    int row0 = tile * 16;
    int q = lane >> 4;
    int l16 = lane & 15;

    short8 bf[NT][KC];
#pragma unroll
    for (int nt = 0; nt < NT; ++nt)
#pragma unroll
        for (int c = 0; c < KC; ++c)
            bf[nt][c] = *(short8*)(lds + ((size_t)(nt * 3 + c) * 64 + lane) * 8);

    short8 af[KC];
#pragma unroll
    for (int c = 0; c < KC; ++c) {
        const float* ap = x + (size_t)(row0 + l16) * DD + c * 32 + q * 8;
        float4 f0 = *(const float4*)ap;
        float4 f1 = *(const float4*)(ap + 4);
        ushort_t v[8] = {f2bf(f0.x), f2bf(f0.y), f2bf(f0.z), f2bf(f0.w),
                         f2bf(f1.x), f2bf(f1.y), f2bf(f1.z), f2bf(f1.w)};
        af[c] = *(short8*)v;
    }

    f32x4 acc[NT];
#pragma unroll
    for (int nt = 0; nt < NT; ++nt) acc[nt] = (f32x4){0.f, 0.f, 0.f, 0.f};
#pragma unroll
    for (int nt = 0; nt < NT; ++nt)
#pragma unroll
        for (int c = 0; c < KC; ++c)
            acc[nt] = __builtin_amdgcn_mfma_f32_16x16x32_bf16(af[c], bf[nt][c], acc[nt], 0, 0, 0);

    // epilogue: 3 column-slabs [NN][32]
#pragma unroll
    for (int nt = 0; nt < NT; ++nt) {
        int s = nt >> 1;
        int c32 = (nt & 1) * 16 + l16;
#pragma unroll
        for (int r = 0; r < 4; ++r)
            y1[(size_t)s * NN * 32 + (size_t)(row0 + q * 4 + r) * 32 + c32] = f2bf(acc[nt][r]);
    }
}

// ====== k_aggmm: fused agg1 + GEMM2 + GEMM3; ELL built in-LDS from packed ===================

#define HSTRIDE 104   // 96 + 8 pad shorts

__global__ void k_aggmm(const int* __restrict__ bcnt, const uint_t* __restrict__ packed,
                        const ushort_t* __restrict__ y1, const float* __restrict__ eps_p,
                        const float* __restrict__ b1a, const ushort_t* __restrict__ wf,
                        const float* __restrict__ b1b, ushort_t* __restrict__ y2) {
    constexpr int KC = 3, NT1 = 6, NT2 = 2;
    __shared__ __align__(16) ushort_t hT[64 * HSTRIDE];   // 13.3 KB t1 tile (bf16)
    __shared__ __align__(16) ushort_t erL[64 * ELLW];     // 8 KB ELL rows (built from packed)
    __shared__ int cntL[64];
    int thr = threadIdx.x;
    int i0 = blockIdx.x * 64;

    build_ell_lds(bcnt, packed, i0, thr, erL, cntL);

    int g = thr >> 2;          // node 0..63 within block
    int u = thr & 3;           // 16B chunk within each 32-col slab
    int i = i0 + g;

    if (i < NN) {
        const ushort_t* er = &erL[g * 64];
        int d = min(cntL[g], ELLW);
        float e = 1.0f + eps_p[0];
        const float4* b4 = (const float4*)b1a;
        ushort_t* dstg = &hT[g * HSTRIDE + u * 8];
#pragma unroll 1
        for (int s = 0; s < 3; ++s) {
            const uint4* ysS = (const uint4*)(y1 + (size_t)s * NN * 32);
            float a0[8] = {0,0,0,0,0,0,0,0}, a1[8] = {0,0,0,0,0,0,0,0};
            float a2[8] = {0,0,0,0,0,0,0,0}, a3[8] = {0,0,0,0,0,0,0,0};
            int p = 0;
            for (; p + 3 < d; p += 4) {
                int s0 = er[p], s1 = er[p + 1], s2 = er[p + 2], s3 = er[p + 3];
                uint4 f0 = ysS[(size_t)s0 * 4 + u];
                uint4 f1 = ysS[(size_t)s1 * 4 + u];
                uint4 f2 = ysS[(size_t)s2 * 4 + u];
                uint4 f3 = ysS[(size_t)s3 * 4 + u];
                addbf8(a0, f0); addbf8(a1, f1); addbf8(a2, f2); addbf8(a3, f3);
            }
            for (; p < d; ++p) addbf8(a0, ysS[(size_t)er[p] * 4 + u]);

            uint4 su = ysS[(size_t)i * 4 + u];
            float s8[8];
            s8[0] = __uint_as_float(su.x << 16); s8[1] = __uint_as_float(su.x & 0xffff0000u);
            s8[2] = __uint_as_float(su.y << 16); s8[3] = __uint_as_float(su.y & 0xffff0000u);
            s8[4] = __uint_as_float(su.z << 16); s8[5] = __uint_as_float(su.z & 0xffff0000u);
            s8[6] = __uint_as_float(su.w << 16); s8[7] = __uint_as_float(su.w & 0xffff0000u);
            float4 bl = b4[s * 8 + u * 2];
            float4 bh2 = b4[s * 8 + u * 2 + 1];
            float bb[8] = {bl.x, bl.y, bl.z, bl.w, bh2.x, bh2.y, bh2.z, bh2.w};
            ushort_t r[8];
#pragma unroll
            for (int k = 0; k < 8; ++k) {
                float vv = fmaf(e, s8[k], (a0[k] + a1[k]) + (a2[k] + a3[k])) + bb[k];
                r[k] = f2bf(fmaxf(vv, 0.0f));
            }
            *(uint4*)(dstg + s * 32) = *(uint4*)r;
        }
    }
    __syncthreads();

    // ---- phase 2: GEMM2+3 on the LDS t1 tile ----
    int lane = thr & 63;
    int widx = thr >> 6;
    int tile = blockIdx.x * 4 + widx;
    if (tile >= MT1) return;
    int row0 = tile * 16;
    int q = lane >> 4;
    int l16 = lane & 15;
    const short8* bfp1 = (const short8*)wf;
    const short8* bfp2 = (const short8*)(wf + 9216);

    short8 bf[NT1][KC];
#pragma unroll
    for (int nt = 0; nt < NT1; ++nt)
#pragma unroll
        for (int c = 0; c < KC; ++c)
            bf[nt][c] = bfp1[(nt * KC + c) * 64 + lane];

    short8 af2[KC];
#pragma unroll
    for (int c = 0; c < KC; ++c) {
        uint4 av = *(const uint4*)&hT[(widx * 16 + l16) * HSTRIDE + c * 32 + q * 8];
        af2[c] = *(short8*)&av;
    }

    f32x4 acc[NT1];
#pragma unroll
    for (int nt = 0; nt < NT1; ++nt) acc[nt] = (f32x4){0.f, 0.f, 0.f, 0.f};
#pragma unroll
    for (int nt = 0; nt < NT1; ++nt)
#pragma unroll
        for (int c = 0; c < KC; ++c)
            acc[nt] = __builtin_amdgcn_mfma_f32_16x16x32_bf16(af2[c], bf[nt][c], acc[nt], 0, 0, 0);

    __syncthreads();
#pragma unroll
    for (int nt = 0; nt < NT1; ++nt) {
        int col = nt * 16 + l16;
        float bv = b1b[col];
#pragma unroll
        for (int r = 0; r < 4; ++r)
            hT[(widx * 16 + q * 4 + r) * HSTRIDE + col] = f2bf(fmaxf(acc[nt][r] + bv, 0.0f));
    }
    __syncthreads();

    short8 af3[KC];
#pragma unroll
    for (int c = 0; c < KC; ++c) {
        uint4 av = *(const uint4*)&hT[(widx * 16 + l16) * HSTRIDE + c * 32 + q * 8];
        af3[c] = *(short8*)&av;
    }
    short8 bf2[NT2][KC];
#pragma unroll
    for (int nt = 0; nt < NT2; ++nt)
#pragma unroll
        for (int c = 0; c < KC; ++c)
            bf2[nt][c] = bfp2[(nt * KC + c) * 64 + lane];

    f32x4 acc2[NT2];
#pragma unroll
    for (int nt = 0; nt < NT2; ++nt) acc2[nt] = (f32x4){0.f, 0.f, 0.f, 0.f};
#pragma unroll
    for (int nt = 0; nt < NT2; ++nt)
#pragma unroll
        for (int c = 0; c < KC; ++c)
            acc2[nt] = __builtin_amdgcn_mfma_f32_16x16x32_bf16(af3[c], bf2[nt][c], acc2[nt], 0, 0, 0);

#pragma unroll
    for (int nt = 0; nt < NT2; ++nt) {
        int col = nt * 16 + l16;
#pragma unroll
        for (int r = 0; r < 4; ++r)
            y2[(size_t)(row0 + q * 4 + r) * HH + col] = f2bf(acc2[nt][r]);
    }
}

// ====== k_agg2tail: fused agg2 + MFMA tail; ELL built in-LDS from packed ====================

#define TS2 40        // 32 + 8 pad shorts

__global__ void k_agg2tail(const int* __restrict__ bcnt, const uint_t* __restrict__ packed,
                           const ushort_t* __restrict__ y2, const float* __restrict__ eps_p,
                           const float* __restrict__ b2a, const float* __restrict__ b2b,
                           const float* __restrict__ bhp, const ushort_t* __restrict__ wf,
                           float* __restrict__ out) {
    __shared__ __align__(16) ushort_t erL[64 * ELLW];     // 8 KB
    __shared__ int cntL[64];
    __shared__ __align__(16) ushort_t t2T[64 * TS2];      // 5 KB t2 tile (bf16)
    __shared__ __align__(16) ushort_t hB[4][16 * TS2];    // 5 KB h2 bounce
    int thr = threadIdx.x;
    int i0 = blockIdx.x * 64;

    build_ell_lds(bcnt, packed, i0, thr, erL, cntL);

    int g = thr >> 2;
    int u = thr & 3;
    int i = i0 + g;

    if (i < NN) {
        const ushort_t* er = &erL[g * 64];
        int d = min(cntL[g], ELLW);
        const uint4* y4 = (const uint4*)y2;
        float a0[8] = {0,0,0,0,0,0,0,0}, a1[8] = {0,0,0,0,0,0,0,0};
        float a2[8] = {0,0,0,0,0,0,0,0}, a3[8] = {0,0,0,0,0,0,0,0};
        int p = 0;
        for (; p + 3 < d; p += 4) {
            int s0 = er[p], s1 = er[p + 1], s2 = er[p + 2], s3 = er[p + 3];
            uint4 f0 = y4[(size_t)s0 * 4 + u];
            uint4 f1 = y4[(size_t)s1 * 4 + u];
            uint4 f2 = y4[(size_t)s2 * 4 + u];
            uint4 f3 = y4[(size_t)s3 * 4 + u];
            addbf8(a0, f0); addbf8(a1, f1); addbf8(a2, f2); addbf8(a3, f3);
        }
        for (; p < d; ++p) addbf8(a0, y4[(size_t)er[p] * 4 + u]);

        uint4 su = y4[(size_t)i * 4 + u];
        float s8[8];
        s8[0] = __uint_as_float(su.x << 16); s8[1] = __uint_as_float(su.x & 0xffff0000u);
        s8[2] = __uint_as_float(su.y << 16); s8[3] = __uint_as_float(su.y & 0xffff0000u);
        s8[4] = __uint_as_float(su.z << 16); s8[5] = __uint_as_float(su.z & 0xffff0000u);
        s8[6] = __uint_as_float(su.w << 16); s8[7] = __uint_as_float(su.w & 0xffff0000u);
        float4 bl = ((const float4*)b2a)[u * 2];
        float4 bh2 = ((const float4*)b2a)[u * 2 + 1];
        float bb[8] = {bl.x, bl.y, bl.z, bl.w, bh2.x, bh2.y, bh2.z, bh2.w};
        float e = 1.0f + eps_p[0];
        ushort_t r[8];
#pragma unroll
        for (int k = 0; k < 8; ++k) {
            float vv = fmaf(e, s8[k], (a0[k] + a1[k]) + (a2[k] + a3[k])) + bb[k];
            r[k] = f2bf(fmaxf(vv, 0.0f));
        }
        *(uint4*)&t2T[g * TS2 + u * 8] = *(uint4*)r;
    }
    __syncthreads();

    // ---- phase 2: MFMA tail ----
    int lane = thr & 63;
    int widx = thr >> 6;
    int tile = blockIdx.x * 4 + widx;
    if (tile >= MT1) return;
    int row0 = tile * 16;
    int q = lane >> 4;
    int l16 = lane & 15;

    uint4 av = *(const uint4*)&t2T[(widx * 16 + l16) * TS2 + q * 8];
    short8 afA = *(short8*)&av;
    const short8* bfW2b = (const short8*)(wf + 12288);
    const short8* bfWh  = (const short8*)(wf + 13312);

    f32x4 acc2[2];
#pragma unroll
    for (int nt = 0; nt < 2; ++nt) {
        acc2[nt] = (f32x4){0.f, 0.f, 0.f, 0.f};
        acc2[nt] = __builtin_amdgcn_mfma_f32_16x16x32_bf16(afA, bfW2b[nt * 64 + lane],
                                                           acc2[nt], 0, 0, 0);
    }

    // h2 = relu(acc2 + b2b) -> per-wave LDS bounce (intra-wave only; no barrier needed)
#pragma unroll
    for (int nt = 0; nt < 2; ++nt) {
        int col = nt * 16 + l16;
        float bv = b2b[col];
#pragma unroll
        for (int r = 0; r < 4; ++r)
            hB[widx][(q * 4 + r) * TS2 + col] = f2bf(fmaxf(acc2[nt][r] + bv, 0.0f));
    }

    uint4 av2 = *(const uint4*)&hB[widx][l16 * TS2 + q * 8];
    short8 afH = *(short8*)&av2;
    f32x4 acch = (f32x4){0.f, 0.f, 0.f, 0.f};
    acch = __builtin_amdgcn_mfma_f32_16x16x32_bf16(afH, bfWh[lane], acch, 0, 0, 0);

    if (l16 < OO) {
        float bv = bhp[l16];
#pragma unroll
        for (int r = 0; r < 4; ++r)
            out[(size_t)(row0 + q * 4 + r) * OO + l16] = acch[r] + bv;
    }
}

// ================= launch =================

extern "C" void kernel_launch(void* const* d_in, const int* in_sizes, int n_in,
                              void* d_out, int out_size, void* d_ws, size_t ws_size,
                              hipStream_t stream) {
    const float* x    = (const float*)d_in[0];
    const int*   edges= (const int*)d_in[1];
    const float* eps1 = (const float*)d_in[2];
    const float* eps2 = (const float*)d_in[3];
    const float* W1a  = (const float*)d_in[4];
    const float* b1a  = (const float*)d_in[5];
    const float* W1b  = (const float*)d_in[6];
    const float* b1b  = (const float*)d_in[7];
    const float* W2a  = (const float*)d_in[8];
    const float* b2a  = (const float*)d_in[9];
    const float* W2b  = (const float*)d_in[10];
    const float* b2b  = (const float*)d_in[11];
    const float* Wh   = (const float*)d_in[12];
    const float* bh   = (const float*)d_in[13];

    auto al = [](size_t n) { return (n + 255) / 256 * 256; };
    char* w = (char*)d_ws;
    int*      bcnt   = (int*)w;      w += al((size_t)NBUCK * 4);
    uint_t*   packed = (uint_t*)w;   w += al((size_t)NBUCK * BCAP * 4);
    ushort_t* wf     = (ushort_t*)w; w += al((size_t)13824 * 2);
    ushort_t* y1     = (ushort_t*)w; w += al((size_t)NN * DD * 2);   // 3 slabs of [NN][32]
    ushort_t* y2     = (ushort_t*)w; w += al((size_t)NN * HH * 2);

    hipMemsetAsync(bcnt, 0, (size_t)NBUCK * 4, stream);
    k1<<<BA_B + WF_B + MFMA1_B, 256, 0, stream>>>(edges, bcnt, packed, W1b, W2a, W2b, Wh,
                                                  wf, x, W1a, y1);
    k_aggmm<<<MFMA1_B, 256, 0, stream>>>(bcnt, packed, y1, eps1, b1a, wf, b1b, y2);
    k_agg2tail<<<MFMA1_B, 256, 0, stream>>>(bcnt, packed, y2, eps2, b2a, b2b, bh, wf,
                                            (float*)d_out);
}